// Round 14
// baseline (483.864 us; speedup 1.0000x reference)
//
#include <hip/hip_runtime.h>
#include <hip/hip_bf16.h>

#define S_LEN 2048
#define HID   4096
#define NH    32
#define HD    128
#define KD    4096

typedef __attribute__((ext_vector_type(4))) float f32x4;
typedef __attribute__((ext_vector_type(8))) short s16x8;
typedef __attribute__((ext_vector_type(4))) short s16x4;

#define AS1 __attribute__((address_space(1)))
#define AS3 __attribute__((address_space(3)))

__device__ __forceinline__ void gl_lds16(const void* g, void* l) {
  __builtin_amdgcn_global_load_lds((const AS1 void*)g, (AS3 void*)l, 16, 0, 0);
}

__device__ inline short f2bf(float f) {
  union { float f; unsigned u; } v; v.f = f;
  return (short)((v.u + 0x7fffu + ((v.u >> 16) & 1u)) >> 16);
}
__device__ inline float bf2f(short s) {
  union { unsigned u; float f; } v; v.u = ((unsigned)(unsigned short)s) << 16;
  return v.f;
}
__device__ inline unsigned packbf(float a, float b) {
  return (unsigned)(unsigned short)f2bf(a) | ((unsigned)(unsigned short)f2bf(b) << 16);
}

// ============ one-time converts ============
__global__ __launch_bounds__(256)
void cvt_kernel(const float* __restrict__ A, short* __restrict__ Ab) {
  const size_t i = ((size_t)blockIdx.x * 256 + threadIdx.x) * 8;
  f32x4 v0 = *(const f32x4*)&A[i];
  f32x4 v1 = *(const f32x4*)&A[i + 4];
  s16x8 r;
  r[0]=f2bf(v0[0]); r[1]=f2bf(v0[1]); r[2]=f2bf(v0[2]); r[3]=f2bf(v0[3]);
  r[4]=f2bf(v1[0]); r[5]=f2bf(v1[1]); r[6]=f2bf(v1[2]); r[7]=f2bf(v1[3]);
  *(s16x8*)&Ab[i] = r;
}

// W [KD][N] f32 -> Wt [N][KD] bf16
__global__ __launch_bounds__(256)
void transcvt_kernel(const float* __restrict__ W, short* __restrict__ Wt, const int N) {
  __shared__ float tile[64][65];
  const int k0 = blockIdx.x * 64, n0 = blockIdx.y * 64;
  const int t = threadIdx.x;
#pragma unroll
  for (int i = 0; i < 16; ++i) {
    const int e = i * 256 + t;
    const int k = e >> 6, n = e & 63;
    tile[n][k] = W[(size_t)(k0 + k) * N + n0 + n];
  }
  __syncthreads();
  const int nn = t >> 2, ks = (t & 3) * 16;
  s16x8 a, b;
#pragma unroll
  for (int i = 0; i < 8; i++) a[i] = f2bf(tile[nn][ks + i]);
#pragma unroll
  for (int i = 0; i < 8; i++) b[i] = f2bf(tile[nn][ks + 8 + i]);
  *(s16x8*)&Wt[(size_t)(n0 + nn) * KD + k0 + ks]     = a;
  *(s16x8*)&Wt[(size_t)(n0 + nn) * KD + k0 + ks + 8] = b;
}

// ============ gemm10: BM=256 BN=128, 8 waves (4Mx2N), wave-tile 64x64, ring-6, ============
// 2 K-tiles per sync: {vmcnt(6); barrier; stage 2 tiles; compute 2 tiles}.
// Slots: tile t -> slot t%6 (pairs P0=(0,1) P1=(2,3) P2=(4,5)); stage targets the pair
// computed in the previous group (freed at this group's barrier). 144KB LDS, 1 block/CU.
template<int EPI>
__global__ __launch_bounds__(512, 1)
void gemm10_kernel(const short* __restrict__ A, const short* __restrict__ Bt,
                   const float* __restrict__ bias,
                   short* __restrict__ Qb, short* __restrict__ Kb, short* __restrict__ Vb,
                   float* __restrict__ Cout)
{
  __shared__ char sm[6][24576] __attribute__((aligned(128)));
  const int KD2 = KD * 2;
  const int bid = blockIdx.x;
  const int xcd = bid & 7, idx = bid >> 3;
  const int m0 = (idx & 7) * 256;
  const int n0 = (xcd * ((EPI == 0) ? 12 : 4) + (idx >> 3)) * 128;

  const int t = threadIdx.x, lane = t & 63, c = lane & 15, g = lane >> 4;
  const int w = t >> 6, wr = w >> 1, wc = w & 1;
  const int flip = ((c >> 1) & 7) << 4;
  const int laneA = wr * 4096 + ((c * 64 + g * 16) ^ flip);
  const int laneB = 16384 + wc * 4096 + ((c * 64 + g * 16) ^ flip);

  const char* srcA[2];
  const char* srcB0;
#pragma unroll
  for (int j = 0; j < 2; ++j) {
    const int la = j * 8192 + t * 16;
    const int ls = la ^ ((la >> 3) & 0x70);
    srcA[j] = (const char*)A + (size_t)(m0 + (ls >> 6)) * KD2 + (ls & 63);
  }
  {
    const int la = t * 16;
    const int ls = la ^ ((la >> 3) & 0x70);
    srcB0 = (const char*)Bt + (size_t)(n0 + (ls >> 6)) * KD2 + (ls & 63);
  }

  f32x4 acc[4][4];
#pragma unroll
  for (int i = 0; i < 4; i++)
#pragma unroll
    for (int j = 0; j < 4; j++) acc[i][j] = (f32x4){0.f, 0.f, 0.f, 0.f};

#define STG(S, H) do {                                        \
    const size_t ko_ = (size_t)(H) * 64;                      \
    gl_lds16(srcA[0] + ko_, sm[S] + t * 16);                  \
    gl_lds16(srcA[1] + ko_, sm[S] + 8192  + t * 16);          \
    gl_lds16(srcB0   + ko_, sm[S] + 16384 + t * 16);          \
  } while (0)

#define COMP(S) do {                                                       \
    const char* b_ = sm[S];                                                \
    s16x8 a_[4], bb_[4];                                                   \
    _Pragma("unroll")                                                      \
    for (int mi = 0; mi < 4; ++mi) a_[mi] = *(const s16x8*)(b_ + laneA + mi * 1024); \
    _Pragma("unroll")                                                      \
    for (int ni = 0; ni < 4; ++ni) bb_[ni] = *(const s16x8*)(b_ + laneB + ni * 1024); \
    __builtin_amdgcn_s_setprio(1);                                         \
    _Pragma("unroll")                                                      \
    for (int mi = 0; mi < 4; ++mi)                                         \
      _Pragma("unroll")                                                    \
      for (int ni = 0; ni < 4; ++ni)                                       \
        acc[mi][ni] = __builtin_amdgcn_mfma_f32_16x16x32_bf16(a_[mi], bb_[ni], acc[mi][ni], 0, 0, 0); \
    __builtin_amdgcn_s_setprio(0);                                         \
  } while (0)

#define WAIT6 asm volatile("s_waitcnt vmcnt(6)" ::: "memory")
#define WAIT0 asm volatile("s_waitcnt vmcnt(0)" ::: "memory")
#define BARR  do { __builtin_amdgcn_s_barrier(); asm volatile("" ::: "memory"); } while (0)

// group: compute slot-pair CP (tiles T-4,T-3... by construction), stage tiles T,T+1 into SP
#define GRP(CP, SP, T) do {                                   \
    WAIT6; BARR;                                              \
    STG((SP) * 2,     (T));                                   \
    STG((SP) * 2 + 1, (T) + 1);                               \
    COMP((CP) * 2);                                           \
    COMP((CP) * 2 + 1);                                       \
  } while (0)

  // prologue: tiles 0..3 into slots 0..3 (12 loads)
  STG(0, 0); STG(1, 1); STG(2, 2); STG(3, 3);

  for (int j = 0; j < 20; ++j) {
    const int b6 = 6 * j;
    GRP(0, 2, b6 + 4);   // g=3j  : compute tiles b6+0,1   stage b6+4,5
    GRP(1, 0, b6 + 6);   // g=3j+1: compute tiles b6+2,3   stage b6+6,7
    GRP(2, 1, b6 + 8);   // g=3j+2: compute tiles b6+4,5   stage b6+8,9
  }
  GRP(0, 2, 124);        // g=60: compute 120,121  stage 124,125
  GRP(1, 0, 126);        // g=61: compute 122,123  stage 126,127
  WAIT6; BARR; COMP(4); COMP(5);   // g=62: tiles 124,125
  WAIT0; BARR; COMP(0); COMP(1);   // g=63: tiles 126,127

#undef GRP
#undef STG
#undef COMP
#undef WAIT6
#undef WAIT0
#undef BARR

  if (EPI == 0) {
#pragma unroll
    for (int ni = 0; ni < 4; ++ni) {
      const int ncol = n0 + wc * 64 + ni * 16 + c;
      const int which = ncol >> 12;
      const int h = (ncol >> 7) & 31;
      const int dcl = ncol & 127;
      short* dst = (which == 0) ? Qb : ((which == 1) ? Kb : Vb);
      const float bv = bias[ncol];
#pragma unroll
      for (int mi = 0; mi < 4; ++mi)
#pragma unroll
        for (int jj = 0; jj < 4; ++jj) {
          const int row = m0 + wr * 64 + mi * 16 + g * 4 + jj;
          dst[((size_t)h * S_LEN + row) * HD + dcl] = f2bf(acc[mi][ni][jj] + bv);
        }
    }
  } else {
#pragma unroll
    for (int ni = 0; ni < 4; ++ni) {
      const int ncol = n0 + wc * 64 + ni * 16 + c;
#pragma unroll
      for (int mi = 0; mi < 4; ++mi)
#pragma unroll
        for (int jj = 0; jj < 4; ++jj) {
          const int row = m0 + wr * 64 + mi * 16 + g * 4 + jj;
          Cout[(size_t)row * HID + ncol] = acc[mi][ni][jj];
        }
    }
  }
}

// ============ fallback GEMM (reg-staged) ============
template<int EPI, int ABF16>
__global__ __launch_bounds__(256)
void gemm_kernel(const void* __restrict__ Av, const float* __restrict__ B,
                 const float* __restrict__ bias, const int N,
                 short* __restrict__ Qb, short* __restrict__ Kb, short* __restrict__ Vb,
                 float* __restrict__ Cout)
{
  __shared__ short As[128][40];
  __shared__ short Bs[128][40];
  const int m0 = blockIdx.x * 128;
  const int nb = blockIdx.y * 128;
  const int t  = threadIdx.x;
  const int w = t >> 6, lane = t & 63, c = lane & 15, g = lane >> 4;
  const int wm = (w >> 1) * 64, wn = (w & 1) * 64;

  f32x4 acc[4][4];
#pragma unroll
  for (int i = 0; i < 4; i++)
#pragma unroll
    for (int j = 0; j < 4; j++) acc[i][j] = (f32x4){0.f, 0.f, 0.f, 0.f};

  const int ar = t >> 3;
  const int ac = (t & 7) * 4;
  const int bn = t & 127;
  const int bkq = (t >> 7) * 16;

  for (int k0 = 0; k0 < KD; k0 += 32) {
#pragma unroll
    for (int rr = 0; rr < 4; rr++) {
      const int row = rr * 32 + ar;
      if (ABF16) {
        *(s16x4*)&As[row][ac] =
          *(const s16x4*)((const short*)Av + (size_t)(m0 + row) * KD + k0 + ac);
      } else {
        f32x4 v = *(const f32x4*)((const float*)Av + (size_t)(m0 + row) * KD + k0 + ac);
        s16x4 pk;
        pk[0] = f2bf(v[0]); pk[1] = f2bf(v[1]); pk[2] = f2bf(v[2]); pk[3] = f2bf(v[3]);
        *(s16x4*)&As[row][ac] = pk;
      }
    }
    const float* pB = B + (size_t)(k0 + bkq) * N + nb + bn;
    s16x8 b0, b1;
#pragma unroll
    for (int i = 0; i < 8; i++) b0[i] = f2bf(pB[(size_t)i * N]);
#pragma unroll
    for (int i = 0; i < 8; i++) b1[i] = f2bf(pB[(size_t)(i + 8) * N]);
    *(s16x8*)&Bs[bn][bkq]     = b0;
    *(s16x8*)&Bs[bn][bkq + 8] = b1;
    __syncthreads();
    s16x8 af[4], bfr[4];
#pragma unroll
    for (int i = 0; i < 4; i++) af[i]  = *(const s16x8*)&As[wm + i * 16 + c][g * 8];
#pragma unroll
    for (int i = 0; i < 4; i++) bfr[i] = *(const s16x8*)&Bs[wn + i * 16 + c][g * 8];
#pragma unroll
    for (int mi = 0; mi < 4; mi++)
#pragma unroll
      for (int ni = 0; ni < 4; ni++)
        acc[mi][ni] = __builtin_amdgcn_mfma_f32_16x16x32_bf16(af[mi], bfr[ni], acc[mi][ni], 0, 0, 0);
    __syncthreads();
  }

  if (EPI == 0) {
    const int which = nb >> 12;
    const int h = (nb & 4095) >> 7;
    short* dst = (which == 0) ? Qb : ((which == 1) ? Kb : Vb);
#pragma unroll
    for (int ni = 0; ni < 4; ni++) {
      const int d = wn + ni * 16 + c;
      const float bv = bias[nb + d];
#pragma unroll
      for (int mi = 0; mi < 4; mi++)
#pragma unroll
        for (int j = 0; j < 4; j++) {
          const int row = m0 + wm + mi * 16 + g * 4 + j;
          dst[((size_t)h * S_LEN + row) * HD + d] = f2bf(acc[mi][ni][j] + bv);
        }
    }
  } else {
#pragma unroll
    for (int ni = 0; ni < 4; ni++) {
      const int n = nb + wn + ni * 16 + c;
#pragma unroll
      for (int mi = 0; mi < 4; mi++)
#pragma unroll
        for (int j = 0; j < 4; j++) {
          const int row = m0 + wm + mi * 16 + g * 4 + j;
          Cout[(size_t)row * N + n] = acc[mi][ni][j];
        }
    }
  }
}

// ============ RoPE (Q scale folds 1/sqrt(HD) * log2(e) -> softmax in base 2) ============
__global__ void rope_kernel(const int* __restrict__ positions,
                            short* __restrict__ Qb, short* __restrict__ Kb)
{
  const int s = blockIdx.x;
  const int h = blockIdx.y * 4 + threadIdx.y;
  const int d = threadIdx.x;
  const float pos = (float)positions[s];
  const float inv_freq = exp2f(-(float)d * 0.20762050593046014f);
  const float ang = pos * inv_freq;
  float sn, cs;
  sincosf(ang, &sn, &cs);
  const size_t base = ((size_t)h * S_LEN + s) * HD + d;
  const float scale = 0.12751744416058255f;   // (1/sqrt(128)) * log2(e)
  float x1 = bf2f(Qb[base]), x2 = bf2f(Qb[base + 64]);
  Qb[base]      = f2bf((x1 * cs - x2 * sn) * scale);
  Qb[base + 64] = f2bf((x2 * cs + x1 * sn) * scale);
  x1 = bf2f(Kb[base]); x2 = bf2f(Kb[base + 64]);
  Kb[base]      = f2bf(x1 * cs - x2 * sn);
  Kb[base + 64] = f2bf(x2 * cs + x1 * sn);
}

// ============ V -> Vt [NH][HD][S] ============
__global__ __launch_bounds__(256)
void vtrans_kernel(const short* __restrict__ V, short* __restrict__ Vt)
{
  __shared__ short tile[64][72];
  const int h = blockIdx.z;
  const int s0 = blockIdx.x * 64;
  const int d0 = blockIdx.y * 64;
  const int tx = threadIdx.x & 63, ty = threadIdx.x >> 6;
  for (int r = ty; r < 64; r += 4)
    tile[r][tx] = V[((size_t)h * S_LEN + s0 + r) * HD + d0 + tx];
  __syncthreads();
  for (int r = ty; r < 64; r += 4)
    Vt[((size_t)h * HD + d0 + r) * S_LEN + s0 + tx] = tile[tx][r];
}

// ============ causal flash attention v5: paired q-panels, base-2 softmax, ============
// per-lane partial l (final butterfly only). Scores arrive pre-scaled by log2(e).
__global__ __launch_bounds__(512)
void attn_kernel(const short* __restrict__ Q, const short* __restrict__ Kg,
                 const short* __restrict__ Vtg, short* __restrict__ attn_out)
{
  __shared__ short Ks[2][64][128];
  __shared__ short Vs[2][128][72];
  const int h = blockIdx.y;
  const int ib = blockIdx.x;
  const int q0a = ib * 128;
  const int q0b = (15 - ib) * 128;
  const int nt0 = 2 * ib + 2;
  const int nt1 = 32 - 2 * ib;
  const int t = threadIdx.x;
  const int w = t >> 6, lane = t & 63, c = lane & 15, g = lane >> 4;
  const short* Qh = Q   + (size_t)h * S_LEN * HD;
  const short* Kh = Kg  + (size_t)h * S_LEN * HD;
  const short* Vh = Vtg + (size_t)h * HD * S_LEN;

  const int krow = t >> 4, kch = t & 15;
  const int vrow = t >> 3, vch = t & 7;
  const int ksw = (kch ^ ((krow & 3) | ((krow >> 1) & 4))) * 16;

  const int rbase = (c >> 2) * 8 + (c & 3);
  const int sb = (rbase & 3) | ((rbase >> 1) & 4);
  int koff[4];
#pragma unroll
  for (int di = 0; di < 4; ++di) koff[di] = ((di * 4 + g) ^ sb) * 16;

  const int qga = q0a + w * 16 + c;
  const int qgb = q0b + w * 16 + c;
  s16x8 qfa[4], qfb[4];
#pragma unroll
  for (int di = 0; di < 4; di++) {
    qfa[di] = *(const s16x8*)&Qh[(size_t)qga * HD + di * 32 + g * 8];
    qfb[di] = *(const s16x8*)&Qh[(size_t)qgb * HD + di * 32 + g * 8];
  }

  f32x4 oa[8], ob[8];
#pragma unroll
  for (int dt = 0; dt < 8; dt++) {
    oa[dt] = (f32x4){0.f, 0.f, 0.f, 0.f};
    ob[dt] = (f32x4){0.f, 0.f, 0.f, 0.f};
  }
  float m_a = -3.0e38f, l_a = 0.f, m_b = -3.0e38f, l_b = 0.f;

#define SM_PANEL(SA, SB, SC, SD, QG, FULL, MR, LR, OARR, PB0, PB1) do {        \
    float v_[16];                                                              \
    if (FULL) {                                                                \
      _Pragma("unroll")                                                        \
      for (int j = 0; j < 4; ++j) {                                            \
        v_[j] = SA[j]; v_[4 + j] = SB[j]; v_[8 + j] = SC[j]; v_[12 + j] = SD[j]; \
      }                                                                        \
    } else {                                                                   \
      _Pragma("unroll")                                                        \
      for (int j = 0; j < 4; ++j) {                                            \
        v_[j]      = (kb + 8 * g + j          <= (QG)) ? SA[j] : -__builtin_inff(); \
        v_[4 + j]  = (kb + 8 * g + 4 + j      <= (QG)) ? SB[j] : -__builtin_inff(); \
        v_[8 + j]  = (kb + 32 + 8 * g + j     <= (QG)) ? SC[j] : -__builtin_inff(); \
        v_[12 + j] = (kb + 32 + 8 * g + 4 + j <= (QG)) ? SD[j] : -__builtin_inff(); \
      }                                                                        \
    }                                                                          \
    float mx_ = v_[0];                                                         \
    _Pragma("unroll")                                                          \
    for (int ii = 1; ii < 16; ++ii) mx_ = fmaxf(mx_, v_[ii]);                  \
    mx_ = fmaxf(mx_, __shfl_xor(mx_, 16, 64));                                 \
    mx_ = fmaxf(mx_, __shfl_xor(mx_, 32, 64));                                 \
    const float mn_ = fmaxf(MR, mx_);                                          \
    if (!__all(mn_ - MR <= 8.0f)) {                                            \
      const float al_ = exp2f(MR - mn_);                                       \
      LR *= al_;                                                               \
      _Pragma("unroll")                                                        \
      for (int dt = 0; dt < 8; ++dt)                                           \
        _Pragma("unroll")                                                      \
        for (int j = 0; j < 4; ++j) OARR[dt][j] *= al_;                        \
      MR = mn_;                                                                \
    }                                                                          \
    float p_[16], rs_ = 0.f;                                                   \
    _Pragma("unroll")                                                          \
    for (int ii = 0; ii < 16; ++ii) { p_[ii] = exp2f(v_[ii] - MR); rs_ += p_[ii]; } \
    LR += rs_;                                                                 \
    union { s16x8 v8; unsigned u[4]; } pu0_, pu1_;                             \
    pu0_.u[0] = packbf(p_[0], p_[1]);   pu0_.u[1] = packbf(p_[2], p_[3]);      \
    pu0_.u[2] = packbf(p_[4], p_[5]);   pu0_.u[3] = packbf(p_[6], p_[7]);      \
    pu1_.u[0] = packbf(p_[8], p_[9]);   pu1_.u[1] = packbf(p_[10], p_[11]);    \
    pu1_.u[2] = packbf(p_[12], p_[13]); pu1_.u[3] = packbf(p_[14], p_[15]);    \
    PB0 = pu0_.v8; PB1 = pu1_.v8;                                              \
  } while (0)

  {
#pragma unroll
    for (int i = 0; i < 2; ++i) {
      s16x8 gK = *(const s16x8*)&Kh[(size_t)(i * 32 + krow) * HD + kch * 8];
      s16x8 gV = *(const s16x8*)&Vh[(size_t)(i * 64 + vrow) * S_LEN + vch * 8];
      *(s16x8*)((char*)&Ks[0][0][0] + (i * 32 + krow) * 256 + ksw) = gK;
      *(s16x8*)&Vs[0][i * 64 + vrow][vch * 8] = gV;
    }
  }
  __syncthreads();

  for (int kt = 0; kt < nt1; kt++) {
    const int cur = kt & 1;
    const int kb = kt * 64;
    const bool do0 = (kt < nt0);
    s16x8 gK0, gK1, gV0, gV1;
    if (kt + 1 < nt1) {
      gK0 = *(const s16x8*)&Kh[(size_t)(kb + 64 + krow) * HD + kch * 8];
      gK1 = *(const s16x8*)&Kh[(size_t)(kb + 96 + krow) * HD + kch * 8];
      gV0 = *(const s16x8*)&Vh[(size_t)vrow * S_LEN + kb + 64 + vch * 8];
      gV1 = *(const s16x8*)&Vh[(size_t)(64 + vrow) * S_LEN + kb + 64 + vch * 8];
    }
    f32x4 bA = (f32x4){0,0,0,0}, bB = (f32x4){0,0,0,0};
    f32x4 bC = (f32x4){0,0,0,0}, bD = (f32x4){0,0,0,0};
    f32x4 aA = (f32x4){0,0,0,0}, aB = (f32x4){0,0,0,0};
    f32x4 aC = (f32x4){0,0,0,0}, aD = (f32x4){0,0,0,0};
    const char* kbase = (const char*)&Ks[cur][0][0] + rbase * 256;
    __builtin_amdgcn_s_setprio(1);
    if (do0) {
#pragma unroll
      for (int di = 0; di < 4; ++di) {
        const char* p = kbase + koff[di];
        s16x8 kA = *(const s16x8*)(p);
        s16x8 kB = *(const s16x8*)(p + 1024);
        s16x8 kC = *(const s16x8*)(p + 8192);
        s16x8 kD = *(const s16x8*)(p + 9216);
        bA = __builtin_amdgcn_mfma_f32_16x16x32_bf16(kA, qfb[di], bA, 0, 0, 0);
        bB = __builtin_amdgcn_mfma_f32_16x16x32_bf16(kB, qfb[di], bB, 0, 0, 0);
        bC = __builtin_amdgcn_mfma_f32_16x16x32_bf16(kC, qfb[di], bC, 0, 0, 0);
        bD = __builtin_amdgcn_mfma_f32_16x16x32_bf16(kD, qfb[di], bD, 0, 0, 0);
        aA = __builtin_amdgcn_mfma_f32_16x16x32_bf16(kA, qfa[di], aA, 0, 0, 0);
        aB = __builtin_amdgcn_mfma_f32_16x16x32_bf16(kB, qfa[di], aB, 0, 0, 0);
        aC = __builtin_amdgcn_mfma_f32_16x16x32_bf16(kC, qfa[di], aC, 0, 0, 0);
        aD = __builtin_amdgcn_mfma_f32_16x16x32_bf16(kD, qfa[di], aD, 0, 0, 0);
      }
    } else {
#pragma unroll
      for (int di = 0; di < 4; ++di) {
        const char* p = kbase + koff[di];
        s16x8 kA = *(const s16x8*)(p);
        s16x8 kB = *(const s16x8*)(p + 1024);
        s16x8 kC = *(const s16x8*)(p + 8192);
        s16x8 kD = *(const s16x8*)(p + 9216);
        bA = __builtin_amdgcn_mfma_f32_16x16x32_bf16(kA, qfb[di], bA, 0, 0, 0);
        bB = __builtin_amdgcn_mfma_f32_16x16x32_bf16(kB, qfb[di], bB, 0, 0, 0);
        bC = __builtin_amdgcn_mfma_f32_16x16x32_bf16(kC, qfb[di], bC, 0, 0, 0);
        bD = __builtin_amdgcn_mfma_f32_16x16x32_bf16(kD, qfb[di], bD, 0, 0, 0);
      }
    }
    __builtin_amdgcn_s_setprio(0);
    s16x8 pb0, pb1, pa0, pa1;
    const bool fullb = (kb + 64 <= q0b);
    SM_PANEL(bA, bB, bC, bD, qgb, fullb, m_b, l_b, ob, pb0, pb1);
    if (do0) {
      const bool fulla = (kb + 64 <= q0a);
      SM_PANEL(aA, aB, aC, aD, qga, fulla, m_a, l_a, oa, pa0, pa1);
    }
    __builtin_amdgcn_s_setprio(1);
    if (do0) {
#pragma unroll
      for (int dt = 0; dt < 8; dt++) {
        s16x8 vf0 = *(const s16x8*)&Vs[cur][dt * 16 + c][g * 8];
        s16x8 vf1 = *(const s16x8*)&Vs[cur][dt * 16 + c][32 + g * 8];
        ob[dt] = __builtin_amdgcn_mfma_f32_16x16x32_bf16(vf0, pb0, ob[dt], 0, 0, 0);
        ob[dt] = __builtin_amdgcn_mfma_f32_16x16x32_bf16(vf1, pb1, ob[dt], 0, 0, 0);
        oa[dt] = __builtin_amdgcn_mfma_f32_16x16x32_bf16(vf0, pa0, oa[dt], 0, 0, 0);
        oa[dt] = __builtin_amdgcn_mfma_f32_16x16x32_bf16(vf1, pa1, oa[dt], 0, 0, 0);
      }
    } else {
#pragma unroll
      for (int dt = 0; dt < 8; dt++) {
        s16x8 vf0 = *(const s16x8*)&Vs[cur][dt * 16 + c][g * 8];
        s16x8 vf1 = *(const s16x8*)&Vs[cur][dt * 16 + c][32 + g * 8];
        ob[dt] = __builtin_amdgcn_mfma_f32_16x16x32_bf16(vf0, pb0, ob[dt], 0, 0, 0);
        ob[dt] = __builtin_amdgcn_mfma_f32_16x16x32_bf16(vf1, pb1, ob[dt], 0, 0, 0);
      }
    }
    __builtin_amdgcn_s_setprio(0);
    __syncthreads();
    if (kt + 1 < nt1) {
      *(s16x8*)((char*)&Ks[cur ^ 1][0][0] + krow * 256 + ksw)        = gK0;
      *(s16x8*)((char*)&Ks[cur ^ 1][0][0] + (32 + krow) * 256 + ksw) = gK1;
      *(s16x8*)&Vs[cur ^ 1][vrow][vch * 8]      = gV0;
      *(s16x8*)&Vs[cur ^ 1][64 + vrow][vch * 8] = gV1;
    }
    __syncthreads();
  }
#undef SM_PANEL

  l_b += __shfl_xor(l_b, 16, 64);  l_b += __shfl_xor(l_b, 32, 64);
  l_a += __shfl_xor(l_a, 16, 64);  l_a += __shfl_xor(l_a, 32, 64);
  const float inv_b = 1.0f / l_b;
  const float inv_a = 1.0f / l_a;
#pragma unroll
  for (int dt = 0; dt < 8; dt++) {
    s16x4 pkb, pka;
#pragma unroll
    for (int j = 0; j < 4; j++) {
      pkb[j] = f2bf(ob[dt][j] * inv_b);
      pka[j] = f2bf(oa[dt][j] * inv_a);
    }
    *(s16x4*)&attn_out[(size_t)qgb * HID + h * HD + dt * 16 + g * 4] = pkb;
    *(s16x4*)&attn_out[(size_t)qga * HID + h * HD + dt * 16 + g * 4] = pka;
  }
}

extern "C" void kernel_launch(void* const* d_in, const int* in_sizes, int n_in,
                              void* d_out, int out_size, void* d_ws, size_t ws_size,
                              hipStream_t stream)
{
  const int*   positions = (const int*)d_in[0];
  const float* hidden    = (const float*)d_in[1];
  const float* w_qkv     = (const float*)d_in[2];
  const float* b_qkv     = (const float*)d_in[3];
  const float* w_o       = (const float*)d_in[4];
  float* out = (float*)d_out;

  char* ws = (char*)d_ws;
  const size_t MB = (size_t)1 << 20;

  if (ws_size >= 224 * MB) {
    short* Ah    = (short*)(ws);                 // 16 MB  bf16 [S][KD]
    short* Wqt   = (short*)(ws + 16 * MB);       // 96 MB  bf16 [3*HID][KD]
    short* Wot   = (short*)(ws + 112 * MB);      // 32 MB  bf16 [HID][KD]
    short* Qb    = (short*)(ws + 144 * MB);      // 16 MB
    short* Kb    = (short*)(ws + 160 * MB);      // 16 MB
    short* Vb    = (short*)(ws + 176 * MB);      // 16 MB
    short* Vt    = (short*)(ws + 192 * MB);      // 16 MB
    short* attnb = (short*)(ws + 208 * MB);      // 16 MB  bf16 [S][HID]

    cvt_kernel<<<4096, 256, 0, stream>>>(hidden, Ah);
    transcvt_kernel<<<dim3(KD / 64, 3 * HID / 64), 256, 0, stream>>>(w_qkv, Wqt, 3 * HID);
    transcvt_kernel<<<dim3(KD / 64, HID / 64), 256, 0, stream>>>(w_o, Wot, HID);
    gemm10_kernel<0><<<768, 512, 0, stream>>>(Ah, Wqt, b_qkv, Qb, Kb, Vb, nullptr);
    rope_kernel<<<dim3(S_LEN, NH / 4), dim3(64, 4), 0, stream>>>(positions, Qb, Kb);
    vtrans_kernel<<<dim3(S_LEN / 64, HD / 64, NH), 256, 0, stream>>>(Vb, Vt);
    attn_kernel<<<dim3(8, NH), 512, 0, stream>>>(Qb, Kb, Vt, attnb);
    gemm10_kernel<1><<<256, 512, 0, stream>>>(attnb, Wot, nullptr,
                                              nullptr, nullptr, nullptr, out);
  } else {
    short* Qb    = (short*)(ws);
    short* Kb    = (short*)(ws + 16 * MB);
    short* Vb    = (short*)(ws + 32 * MB);
    short* Vt    = (short*)(ws + 48 * MB);
    short* attnb = (short*)(ws + 64 * MB);

    gemm_kernel<0, 0><<<dim3(16, 96), 256, 0, stream>>>(hidden, w_qkv, b_qkv, 3 * HID,
                                                        Qb, Kb, Vb, nullptr);
    rope_kernel<<<dim3(S_LEN, NH / 4), dim3(64, 4), 0, stream>>>(positions, Qb, Kb);
    vtrans_kernel<<<dim3(S_LEN / 64, HD / 64, NH), 256, 0, stream>>>(Vb, Vt);
    attn_kernel<<<dim3(8, NH), 512, 0, stream>>>(Qb, Kb, Vt, attnb);
    gemm_kernel<1, 1><<<dim3(16, 32), 256, 0, stream>>>(attnb, w_o, nullptr, HID,
                                                        nullptr, nullptr, nullptr, out);
  }
}

// Round 15
// 462.057 us; speedup vs baseline: 1.0472x; 1.0472x over previous
//
#include <hip/hip_runtime.h>
#include <hip/hip_bf16.h>

#define S_LEN 2048
#define HID   4096
#define NH    32
#define HD    128
#define KD    4096

typedef __attribute__((ext_vector_type(4))) float f32x4;
typedef __attribute__((ext_vector_type(8))) short s16x8;
typedef __attribute__((ext_vector_type(4))) short s16x4;

#define AS1 __attribute__((address_space(1)))
#define AS3 __attribute__((address_space(3)))

__device__ __forceinline__ void gl_lds16(const void* g, void* l) {
  __builtin_amdgcn_global_load_lds((const AS1 void*)g, (AS3 void*)l, 16, 0, 0);
}

__device__ inline short f2bf(float f) {
  union { float f; unsigned u; } v; v.f = f;
  return (short)((v.u + 0x7fffu + ((v.u >> 16) & 1u)) >> 16);
}
__device__ inline float bf2f(short s) {
  union { unsigned u; float f; } v; v.u = ((unsigned)(unsigned short)s) << 16;
  return v.f;
}
__device__ inline unsigned packbf(float a, float b) {
  return (unsigned)(unsigned short)f2bf(a) | ((unsigned)(unsigned short)f2bf(b) << 16);
}

// ============ one-time converts ============
__global__ __launch_bounds__(256)
void cvt_kernel(const float* __restrict__ A, short* __restrict__ Ab) {
  const size_t i = ((size_t)blockIdx.x * 256 + threadIdx.x) * 8;
  f32x4 v0 = *(const f32x4*)&A[i];
  f32x4 v1 = *(const f32x4*)&A[i + 4];
  s16x8 r;
  r[0]=f2bf(v0[0]); r[1]=f2bf(v0[1]); r[2]=f2bf(v0[2]); r[3]=f2bf(v0[3]);
  r[4]=f2bf(v1[0]); r[5]=f2bf(v1[1]); r[6]=f2bf(v1[2]); r[7]=f2bf(v1[3]);
  *(s16x8*)&Ab[i] = r;
}

// W [KD][N] f32 -> Wt [N][KD] bf16
__global__ __launch_bounds__(256)
void transcvt_kernel(const float* __restrict__ W, short* __restrict__ Wt, const int N) {
  __shared__ float tile[64][65];
  const int k0 = blockIdx.x * 64, n0 = blockIdx.y * 64;
  const int t = threadIdx.x;
#pragma unroll
  for (int i = 0; i < 16; ++i) {
    const int e = i * 256 + t;
    const int k = e >> 6, n = e & 63;
    tile[n][k] = W[(size_t)(k0 + k) * N + n0 + n];
  }
  __syncthreads();
  const int nn = t >> 2, ks = (t & 3) * 16;
  s16x8 a, b;
#pragma unroll
  for (int i = 0; i < 8; i++) a[i] = f2bf(tile[nn][ks + i]);
#pragma unroll
  for (int i = 0; i < 8; i++) b[i] = f2bf(tile[nn][ks + 8 + i]);
  *(s16x8*)&Wt[(size_t)(n0 + nn) * KD + k0 + ks]     = a;
  *(s16x8*)&Wt[(size_t)(n0 + nn) * KD + k0 + ks + 8] = b;
}

// ============ gemm9: BM=256 BN=128, 8 waves (4Mx2N), wave-tile 64x64, ring-3, ============
// counted vmcnt(3), XOR-swizzled LDS, 2 blocks/CU. V written DIRECTLY transposed to Vt.
template<int EPI>
__global__ __launch_bounds__(512, 4)
void gemm9_kernel(const short* __restrict__ A, const short* __restrict__ Bt,
                  const float* __restrict__ bias,
                  short* __restrict__ Qb, short* __restrict__ Kb, short* __restrict__ Vt,
                  float* __restrict__ Cout)
{
  __shared__ char sm[3][24576] __attribute__((aligned(128)));
  const int KD2 = KD * 2;
  const int bid = blockIdx.x;
  const int xcd = bid & 7, idx = bid >> 3;
  const int m0 = (idx & 7) * 256;
  const int n0 = (xcd * ((EPI == 0) ? 12 : 4) + (idx >> 3)) * 128;

  const int t = threadIdx.x, lane = t & 63, c = lane & 15, g = lane >> 4;
  const int w = t >> 6, wr = w >> 1, wc = w & 1;
  const int flip = ((c >> 1) & 7) << 4;
  const int laneA = wr * 4096 + ((c * 64 + g * 16) ^ flip);
  const int laneB = 16384 + wc * 4096 + ((c * 64 + g * 16) ^ flip);

  const char* srcA[2];
  const char* srcB0;
#pragma unroll
  for (int j = 0; j < 2; ++j) {
    const int la = j * 8192 + t * 16;
    const int ls = la ^ ((la >> 3) & 0x70);
    srcA[j] = (const char*)A + (size_t)(m0 + (ls >> 6)) * KD2 + (ls & 63);
  }
  {
    const int la = t * 16;
    const int ls = la ^ ((la >> 3) & 0x70);
    srcB0 = (const char*)Bt + (size_t)(n0 + (ls >> 6)) * KD2 + (ls & 63);
  }

  f32x4 acc[4][4];
#pragma unroll
  for (int i = 0; i < 4; i++)
#pragma unroll
    for (int j = 0; j < 4; j++) acc[i][j] = (f32x4){0.f, 0.f, 0.f, 0.f};

#define STG9(S, H) do {                                       \
    const size_t ko_ = (size_t)(H) * 64;                      \
    gl_lds16(srcA[0] + ko_, sm[S] + t * 16);                  \
    gl_lds16(srcA[1] + ko_, sm[S] + 8192  + t * 16);          \
    gl_lds16(srcB0   + ko_, sm[S] + 16384 + t * 16);          \
  } while (0)

#define COMP9(S) do {                                                      \
    const char* b_ = sm[S];                                                \
    s16x8 a_[4], bb_[4];                                                   \
    _Pragma("unroll")                                                      \
    for (int mi = 0; mi < 4; ++mi) a_[mi] = *(const s16x8*)(b_ + laneA + mi * 1024); \
    _Pragma("unroll")                                                      \
    for (int ni = 0; ni < 4; ++ni) bb_[ni] = *(const s16x8*)(b_ + laneB + ni * 1024); \
    __builtin_amdgcn_s_setprio(1);                                         \
    _Pragma("unroll")                                                      \
    for (int mi = 0; mi < 4; ++mi)                                         \
      _Pragma("unroll")                                                    \
      for (int ni = 0; ni < 4; ++ni)                                       \
        acc[mi][ni] = __builtin_amdgcn_mfma_f32_16x16x32_bf16(a_[mi], bb_[ni], acc[mi][ni], 0, 0, 0); \
    __builtin_amdgcn_s_setprio(0);                                         \
  } while (0)

#define WAIT3 asm volatile("s_waitcnt vmcnt(3)" ::: "memory")
#define WAIT0 asm volatile("s_waitcnt vmcnt(0)" ::: "memory")
#define BARR  do { __builtin_amdgcn_s_barrier(); asm volatile("" ::: "memory"); } while (0)

  STG9(0, 0); STG9(1, 1);
  for (int j = 0; j < 42; ++j) {
    const int h = 3 * j;
    WAIT3; BARR; STG9(2, h + 2); COMP9(0);
    WAIT3; BARR; STG9(0, h + 3); COMP9(1);
    WAIT3; BARR; STG9(1, h + 4); COMP9(2);
  }
  WAIT3; BARR; COMP9(0);
  WAIT0; BARR; COMP9(1);

#undef STG9
#undef COMP9
#undef WAIT3
#undef WAIT0
#undef BARR

  if (EPI == 0) {
    const int which = n0 >> 12;        // block-uniform (n0 is 128-aligned)
    if (which == 2) {
      // V: write directly transposed -> Vt[h][d][s]
#pragma unroll
      for (int ni = 0; ni < 4; ++ni) {
        const int ncol = n0 + wc * 64 + ni * 16 + c;
        const int h = (ncol >> 7) & 31;
        const int dcl = ncol & 127;
        const float bv = bias[ncol];
#pragma unroll
        for (int mi = 0; mi < 4; ++mi) {
          const int row0 = m0 + wr * 64 + mi * 16 + g * 4;
          s16x4 pk;
#pragma unroll
          for (int jj = 0; jj < 4; ++jj) pk[jj] = f2bf(acc[mi][ni][jj] + bv);
          *(s16x4*)&Vt[((size_t)h * HD + dcl) * S_LEN + row0] = pk;
        }
      }
    } else {
      short* dst = (which == 0) ? Qb : Kb;
#pragma unroll
      for (int ni = 0; ni < 4; ++ni) {
        const int ncol = n0 + wc * 64 + ni * 16 + c;
        const int h = (ncol >> 7) & 31;
        const int dcl = ncol & 127;
        const float bv = bias[ncol];
#pragma unroll
        for (int mi = 0; mi < 4; ++mi)
#pragma unroll
          for (int jj = 0; jj < 4; ++jj) {
            const int row = m0 + wr * 64 + mi * 16 + g * 4 + jj;
            dst[((size_t)h * S_LEN + row) * HD + dcl] = f2bf(acc[mi][ni][jj] + bv);
          }
      }
    }
  } else {
#pragma unroll
    for (int ni = 0; ni < 4; ++ni) {
      const int ncol = n0 + wc * 64 + ni * 16 + c;
#pragma unroll
      for (int mi = 0; mi < 4; ++mi)
#pragma unroll
        for (int jj = 0; jj < 4; ++jj) {
          const int row = m0 + wr * 64 + mi * 16 + g * 4 + jj;
          Cout[(size_t)row * HID + ncol] = acc[mi][ni][jj];
        }
    }
  }
}

// ============ fallback GEMM (reg-staged) ============
template<int EPI, int ABF16>
__global__ __launch_bounds__(256)
void gemm_kernel(const void* __restrict__ Av, const float* __restrict__ B,
                 const float* __restrict__ bias, const int N,
                 short* __restrict__ Qb, short* __restrict__ Kb, short* __restrict__ Vb,
                 float* __restrict__ Cout)
{
  __shared__ short As[128][40];
  __shared__ short Bs[128][40];
  const int m0 = blockIdx.x * 128;
  const int nb = blockIdx.y * 128;
  const int t  = threadIdx.x;
  const int w = t >> 6, lane = t & 63, c = lane & 15, g = lane >> 4;
  const int wm = (w >> 1) * 64, wn = (w & 1) * 64;

  f32x4 acc[4][4];
#pragma unroll
  for (int i = 0; i < 4; i++)
#pragma unroll
    for (int j = 0; j < 4; j++) acc[i][j] = (f32x4){0.f, 0.f, 0.f, 0.f};

  const int ar = t >> 3;
  const int ac = (t & 7) * 4;
  const int bn = t & 127;
  const int bkq = (t >> 7) * 16;

  for (int k0 = 0; k0 < KD; k0 += 32) {
#pragma unroll
    for (int rr = 0; rr < 4; rr++) {
      const int row = rr * 32 + ar;
      if (ABF16) {
        *(s16x4*)&As[row][ac] =
          *(const s16x4*)((const short*)Av + (size_t)(m0 + row) * KD + k0 + ac);
      } else {
        f32x4 v = *(const f32x4*)((const float*)Av + (size_t)(m0 + row) * KD + k0 + ac);
        s16x4 pk;
        pk[0] = f2bf(v[0]); pk[1] = f2bf(v[1]); pk[2] = f2bf(v[2]); pk[3] = f2bf(v[3]);
        *(s16x4*)&As[row][ac] = pk;
      }
    }
    const float* pB = B + (size_t)(k0 + bkq) * N + nb + bn;
    s16x8 b0, b1;
#pragma unroll
    for (int i = 0; i < 8; i++) b0[i] = f2bf(pB[(size_t)i * N]);
#pragma unroll
    for (int i = 0; i < 8; i++) b1[i] = f2bf(pB[(size_t)(i + 8) * N]);
    *(s16x8*)&Bs[bn][bkq]     = b0;
    *(s16x8*)&Bs[bn][bkq + 8] = b1;
    __syncthreads();
    s16x8 af[4], bfr[4];
#pragma unroll
    for (int i = 0; i < 4; i++) af[i]  = *(const s16x8*)&As[wm + i * 16 + c][g * 8];
#pragma unroll
    for (int i = 0; i < 4; i++) bfr[i] = *(const s16x8*)&Bs[wn + i * 16 + c][g * 8];
#pragma unroll
    for (int mi = 0; mi < 4; mi++)
#pragma unroll
      for (int ni = 0; ni < 4; ni++)
        acc[mi][ni] = __builtin_amdgcn_mfma_f32_16x16x32_bf16(af[mi], bfr[ni], acc[mi][ni], 0, 0, 0);
    __syncthreads();
  }

  if (EPI == 0) {
    const int which = nb >> 12;
    const int h = (nb & 4095) >> 7;
    short* dst = (which == 0) ? Qb : ((which == 1) ? Kb : Vb);
#pragma unroll
    for (int ni = 0; ni < 4; ni++) {
      const int d = wn + ni * 16 + c;
      const float bv = bias[nb + d];
#pragma unroll
      for (int mi = 0; mi < 4; mi++)
#pragma unroll
        for (int j = 0; j < 4; j++) {
          const int row = m0 + wm + mi * 16 + g * 4 + j;
          dst[((size_t)h * S_LEN + row) * HD + d] = f2bf(acc[mi][ni][j] + bv);
        }
    }
  } else {
#pragma unroll
    for (int ni = 0; ni < 4; ni++) {
      const int n = nb + wn + ni * 16 + c;
#pragma unroll
      for (int mi = 0; mi < 4; mi++)
#pragma unroll
        for (int j = 0; j < 4; j++) {
          const int row = m0 + wm + mi * 16 + g * 4 + j;
          Cout[(size_t)row * N + n] = acc[mi][ni][j];
        }
    }
  }
}

// ============ RoPE (Q scale folds 1/sqrt(HD) * log2(e) -> softmax in base 2) ============
__global__ void rope_kernel(const int* __restrict__ positions,
                            short* __restrict__ Qb, short* __restrict__ Kb)
{
  const int s = blockIdx.x;
  const int h = blockIdx.y * 4 + threadIdx.y;
  const int d = threadIdx.x;
  const float pos = (float)positions[s];
  const float inv_freq = exp2f(-(float)d * 0.20762050593046014f);
  const float ang = pos * inv_freq;
  float sn, cs;
  sincosf(ang, &sn, &cs);
  const size_t base = ((size_t)h * S_LEN + s) * HD + d;
  const float scale = 0.12751744416058255f;   // (1/sqrt(128)) * log2(e)
  float x1 = bf2f(Qb[base]), x2 = bf2f(Qb[base + 64]);
  Qb[base]      = f2bf((x1 * cs - x2 * sn) * scale);
  Qb[base + 64] = f2bf((x2 * cs + x1 * sn) * scale);
  x1 = bf2f(Kb[base]); x2 = bf2f(Kb[base + 64]);
  Kb[base]      = f2bf(x1 * cs - x2 * sn);
  Kb[base + 64] = f2bf(x2 * cs + x1 * sn);
}

// ============ V -> Vt [NH][HD][S] (fallback path only) ============
__global__ __launch_bounds__(256)
void vtrans_kernel(const short* __restrict__ V, short* __restrict__ Vt)
{
  __shared__ short tile[64][72];
  const int h = blockIdx.z;
  const int s0 = blockIdx.x * 64;
  const int d0 = blockIdx.y * 64;
  const int tx = threadIdx.x & 63, ty = threadIdx.x >> 6;
  for (int r = ty; r < 64; r += 4)
    tile[r][tx] = V[((size_t)h * S_LEN + s0 + r) * HD + d0 + tx];
  __syncthreads();
  for (int r = ty; r < 64; r += 4)
    Vt[((size_t)h * HD + d0 + r) * S_LEN + s0 + tx] = tile[tx][r];
}

// ============ causal flash attention v5: paired q-panels, base-2 softmax, ============
// per-lane partial l (final butterfly only). Scores arrive pre-scaled by log2(e).
__global__ __launch_bounds__(512)
void attn_kernel(const short* __restrict__ Q, const short* __restrict__ Kg,
                 const short* __restrict__ Vtg, short* __restrict__ attn_out)
{
  __shared__ short Ks[2][64][128];
  __shared__ short Vs[2][128][72];
  const int h = blockIdx.y;
  const int ib = blockIdx.x;
  const int q0a = ib * 128;
  const int q0b = (15 - ib) * 128;
  const int nt0 = 2 * ib + 2;
  const int nt1 = 32 - 2 * ib;
  const int t = threadIdx.x;
  const int w = t >> 6, lane = t & 63, c = lane & 15, g = lane >> 4;
  const short* Qh = Q   + (size_t)h * S_LEN * HD;
  const short* Kh = Kg  + (size_t)h * S_LEN * HD;
  const short* Vh = Vtg + (size_t)h * HD * S_LEN;

  const int krow = t >> 4, kch = t & 15;
  const int vrow = t >> 3, vch = t & 7;
  const int ksw = (kch ^ ((krow & 3) | ((krow >> 1) & 4))) * 16;

  const int rbase = (c >> 2) * 8 + (c & 3);
  const int sb = (rbase & 3) | ((rbase >> 1) & 4);
  int koff[4];
#pragma unroll
  for (int di = 0; di < 4; ++di) koff[di] = ((di * 4 + g) ^ sb) * 16;

  const int qga = q0a + w * 16 + c;
  const int qgb = q0b + w * 16 + c;
  s16x8 qfa[4], qfb[4];
#pragma unroll
  for (int di = 0; di < 4; di++) {
    qfa[di] = *(const s16x8*)&Qh[(size_t)qga * HD + di * 32 + g * 8];
    qfb[di] = *(const s16x8*)&Qh[(size_t)qgb * HD + di * 32 + g * 8];
  }

  f32x4 oa[8], ob[8];
#pragma unroll
  for (int dt = 0; dt < 8; dt++) {
    oa[dt] = (f32x4){0.f, 0.f, 0.f, 0.f};
    ob[dt] = (f32x4){0.f, 0.f, 0.f, 0.f};
  }
  float m_a = -3.0e38f, l_a = 0.f, m_b = -3.0e38f, l_b = 0.f;

#define SM_PANEL(SA, SB, SC, SD, QG, FULL, MR, LR, OARR, PB0, PB1) do {        \
    float v_[16];                                                              \
    if (FULL) {                                                                \
      _Pragma("unroll")                                                        \
      for (int j = 0; j < 4; ++j) {                                            \
        v_[j] = SA[j]; v_[4 + j] = SB[j]; v_[8 + j] = SC[j]; v_[12 + j] = SD[j]; \
      }                                                                        \
    } else {                                                                   \
      _Pragma("unroll")                                                        \
      for (int j = 0; j < 4; ++j) {                                            \
        v_[j]      = (kb + 8 * g + j          <= (QG)) ? SA[j] : -__builtin_inff(); \
        v_[4 + j]  = (kb + 8 * g + 4 + j      <= (QG)) ? SB[j] : -__builtin_inff(); \
        v_[8 + j]  = (kb + 32 + 8 * g + j     <= (QG)) ? SC[j] : -__builtin_inff(); \
        v_[12 + j] = (kb + 32 + 8 * g + 4 + j <= (QG)) ? SD[j] : -__builtin_inff(); \
      }                                                                        \
    }                                                                          \
    float mx_ = v_[0];                                                         \
    _Pragma("unroll")                                                          \
    for (int ii = 1; ii < 16; ++ii) mx_ = fmaxf(mx_, v_[ii]);                  \
    mx_ = fmaxf(mx_, __shfl_xor(mx_, 16, 64));                                 \
    mx_ = fmaxf(mx_, __shfl_xor(mx_, 32, 64));                                 \
    const float mn_ = fmaxf(MR, mx_);                                          \
    if (!__all(mn_ - MR <= 8.0f)) {                                            \
      const float al_ = exp2f(MR - mn_);                                       \
      LR *= al_;                                                               \
      _Pragma("unroll")                                                        \
      for (int dt = 0; dt < 8; ++dt)                                           \
        _Pragma("unroll")                                                      \
        for (int j = 0; j < 4; ++j) OARR[dt][j] *= al_;                        \
      MR = mn_;                                                                \
    }                                                                          \
    float p_[16], rs_ = 0.f;                                                   \
    _Pragma("unroll")                                                          \
    for (int ii = 0; ii < 16; ++ii) { p_[ii] = exp2f(v_[ii] - MR); rs_ += p_[ii]; } \
    LR += rs_;                                                                 \
    union { s16x8 v8; unsigned u[4]; } pu0_, pu1_;                             \
    pu0_.u[0] = packbf(p_[0], p_[1]);   pu0_.u[1] = packbf(p_[2], p_[3]);      \
    pu0_.u[2] = packbf(p_[4], p_[5]);   pu0_.u[3] = packbf(p_[6], p_[7]);      \
    pu1_.u[0] = packbf(p_[8], p_[9]);   pu1_.u[1] = packbf(p_[10], p_[11]);    \
    pu1_.u[2] = packbf(p_[12], p_[13]); pu1_.u[3] = packbf(p_[14], p_[15]);    \
    PB0 = pu0_.v8; PB1 = pu1_.v8;                                              \
  } while (0)

  {
#pragma unroll
    for (int i = 0; i < 2; ++i) {
      s16x8 gK = *(const s16x8*)&Kh[(size_t)(i * 32 + krow) * HD + kch * 8];
      s16x8 gV = *(const s16x8*)&Vh[(size_t)(i * 64 + vrow) * S_LEN + vch * 8];
      *(s16x8*)((char*)&Ks[0][0][0] + (i * 32 + krow) * 256 + ksw) = gK;
      *(s16x8*)&Vs[0][i * 64 + vrow][vch * 8] = gV;
    }
  }
  __syncthreads();

  for (int kt = 0; kt < nt1; kt++) {
    const int cur = kt & 1;
    const int kb = kt * 64;
    const bool do0 = (kt < nt0);
    s16x8 gK0, gK1, gV0, gV1;
    if (kt + 1 < nt1) {
      gK0 = *(const s16x8*)&Kh[(size_t)(kb + 64 + krow) * HD + kch * 8];
      gK1 = *(const s16x8*)&Kh[(size_t)(kb + 96 + krow) * HD + kch * 8];
      gV0 = *(const s16x8*)&Vh[(size_t)vrow * S_LEN + kb + 64 + vch * 8];
      gV1 = *(const s16x8*)&Vh[(size_t)(64 + vrow) * S_LEN + kb + 64 + vch * 8];
    }
    f32x4 bA = (f32x4){0,0,0,0}, bB = (f32x4){0,0,0,0};
    f32x4 bC = (f32x4){0,0,0,0}, bD = (f32x4){0,0,0,0};
    f32x4 aA = (f32x4){0,0,0,0}, aB = (f32x4){0,0,0,0};
    f32x4 aC = (f32x4){0,0,0,0}, aD = (f32x4){0,0,0,0};
    const char* kbase = (const char*)&Ks[cur][0][0] + rbase * 256;
    __builtin_amdgcn_s_setprio(1);
    if (do0) {
#pragma unroll
      for (int di = 0; di < 4; ++di) {
        const char* p = kbase + koff[di];
        s16x8 kA = *(const s16x8*)(p);
        s16x8 kB = *(const s16x8*)(p + 1024);
        s16x8 kC = *(const s16x8*)(p + 8192);
        s16x8 kD = *(const s16x8*)(p + 9216);
        bA = __builtin_amdgcn_mfma_f32_16x16x32_bf16(kA, qfb[di], bA, 0, 0, 0);
        bB = __builtin_amdgcn_mfma_f32_16x16x32_bf16(kB, qfb[di], bB, 0, 0, 0);
        bC = __builtin_amdgcn_mfma_f32_16x16x32_bf16(kC, qfb[di], bC, 0, 0, 0);
        bD = __builtin_amdgcn_mfma_f32_16x16x32_bf16(kD, qfb[di], bD, 0, 0, 0);
        aA = __builtin_amdgcn_mfma_f32_16x16x32_bf16(kA, qfa[di], aA, 0, 0, 0);
        aB = __builtin_amdgcn_mfma_f32_16x16x32_bf16(kB, qfa[di], aB, 0, 0, 0);
        aC = __builtin_amdgcn_mfma_f32_16x16x32_bf16(kC, qfa[di], aC, 0, 0, 0);
        aD = __builtin_amdgcn_mfma_f32_16x16x32_bf16(kD, qfa[di], aD, 0, 0, 0);
      }
    } else {
#pragma unroll
      for (int di = 0; di < 4; ++di) {
        const char* p = kbase + koff[di];
        s16x8 kA = *(const s16x8*)(p);
        s16x8 kB = *(const s16x8*)(p + 1024);
        s16x8 kC = *(const s16x8*)(p + 8192);
        s16x8 kD = *(const s16x8*)(p + 9216);
        bA = __builtin_amdgcn_mfma_f32_16x16x32_bf16(kA, qfb[di], bA, 0, 0, 0);
        bB = __builtin_amdgcn_mfma_f32_16x16x32_bf16(kB, qfb[di], bB, 0, 0, 0);
        bC = __builtin_amdgcn_mfma_f32_16x16x32_bf16(kC, qfb[di], bC, 0, 0, 0);
        bD = __builtin_amdgcn_mfma_f32_16x16x32_bf16(kD, qfb[di], bD, 0, 0, 0);
      }
    }
    __builtin_amdgcn_s_setprio(0);
    s16x8 pb0, pb1, pa0, pa1;
    const bool fullb = (kb + 64 <= q0b);
    SM_PANEL(bA, bB, bC, bD, qgb, fullb, m_b, l_b, ob, pb0, pb1);
    if (do0) {
      const bool fulla = (kb + 64 <= q0a);
      SM_PANEL(aA, aB, aC, aD, qga, fulla, m_a, l_a, oa, pa0, pa1);
    }
    __builtin_amdgcn_s_setprio(1);
    if (do0) {
#pragma unroll
      for (int dt = 0; dt < 8; dt++) {
        s16x8 vf0 = *(const s16x8*)&Vs[cur][dt * 16 + c][g * 8];
        s16x8 vf1 = *(const s16x8*)&Vs[cur][dt * 16 + c][32 + g * 8];
        ob[dt] = __builtin_amdgcn_mfma_f32_16x16x32_bf16(vf0, pb0, ob[dt], 0, 0, 0);
        ob[dt] = __builtin_amdgcn_mfma_f32_16x16x32_bf16(vf1, pb1, ob[dt], 0, 0, 0);
        oa[dt] = __builtin_amdgcn_mfma_f32_16x16x32_bf16(vf0, pa0, oa[dt], 0, 0, 0);
        oa[dt] = __builtin_amdgcn_mfma_f32_16x16x32_bf16(vf1, pa1, oa[dt], 0, 0, 0);
      }
    } else {
#pragma unroll
      for (int dt = 0; dt < 8; dt++) {
        s16x8 vf0 = *(const s16x8*)&Vs[cur][dt * 16 + c][g * 8];
        s16x8 vf1 = *(const s16x8*)&Vs[cur][dt * 16 + c][32 + g * 8];
        ob[dt] = __builtin_amdgcn_mfma_f32_16x16x32_bf16(vf0, pb0, ob[dt], 0, 0, 0);
        ob[dt] = __builtin_amdgcn_mfma_f32_16x16x32_bf16(vf1, pb1, ob[dt], 0, 0, 0);
      }
    }
    __builtin_amdgcn_s_setprio(0);
    __syncthreads();
    if (kt + 1 < nt1) {
      *(s16x8*)((char*)&Ks[cur ^ 1][0][0] + krow * 256 + ksw)        = gK0;
      *(s16x8*)((char*)&Ks[cur ^ 1][0][0] + (32 + krow) * 256 + ksw) = gK1;
      *(s16x8*)&Vs[cur ^ 1][vrow][vch * 8]      = gV0;
      *(s16x8*)&Vs[cur ^ 1][64 + vrow][vch * 8] = gV1;
    }
    __syncthreads();
  }
#undef SM_PANEL

  l_b += __shfl_xor(l_b, 16, 64);  l_b += __shfl_xor(l_b, 32, 64);
  l_a += __shfl_xor(l_a, 16, 64);  l_a += __shfl_xor(l_a, 32, 64);
  const float inv_b = 1.0f / l_b;
  const float inv_a = 1.0f / l_a;
#pragma unroll
  for (int dt = 0; dt < 8; dt++) {
    s16x4 pkb, pka;
#pragma unroll
    for (int j = 0; j < 4; j++) {
      pkb[j] = f2bf(ob[dt][j] * inv_b);
      pka[j] = f2bf(oa[dt][j] * inv_a);
    }
    *(s16x4*)&attn_out[(size_t)qgb * HID + h * HD + dt * 16 + g * 4] = pkb;
    *(s16x4*)&attn_out[(size_t)qga * HID + h * HD + dt * 16 + g * 4] = pka;
  }
}

extern "C" void kernel_launch(void* const* d_in, const int* in_sizes, int n_in,
                              void* d_out, int out_size, void* d_ws, size_t ws_size,
                              hipStream_t stream)
{
  const int*   positions = (const int*)d_in[0];
  const float* hidden    = (const float*)d_in[1];
  const float* w_qkv     = (const float*)d_in[2];
  const float* b_qkv     = (const float*)d_in[3];
  const float* w_o       = (const float*)d_in[4];
  float* out = (float*)d_out;

  char* ws = (char*)d_ws;
  const size_t MB = (size_t)1 << 20;

  if (ws_size >= 224 * MB) {
    short* Ah    = (short*)(ws);                 // 16 MB  bf16 [S][KD]
    short* Wqt   = (short*)(ws + 16 * MB);       // 96 MB  bf16 [3*HID][KD]
    short* Wot   = (short*)(ws + 112 * MB);      // 32 MB  bf16 [HID][KD]
    short* Qb    = (short*)(ws + 144 * MB);      // 16 MB
    short* Kb    = (short*)(ws + 160 * MB);      // 16 MB
    short* Vt    = (short*)(ws + 192 * MB);      // 16 MB  [NH][HD][S] (written by gemm9)
    short* attnb = (short*)(ws + 208 * MB);      // 16 MB  bf16 [S][HID]

    cvt_kernel<<<4096, 256, 0, stream>>>(hidden, Ah);
    transcvt_kernel<<<dim3(KD / 64, 3 * HID / 64), 256, 0, stream>>>(w_qkv, Wqt, 3 * HID);
    transcvt_kernel<<<dim3(KD / 64, HID / 64), 256, 0, stream>>>(w_o, Wot, HID);
    gemm9_kernel<0><<<768, 512, 0, stream>>>(Ah, Wqt, b_qkv, Qb, Kb, Vt, nullptr);
    rope_kernel<<<dim3(S_LEN, NH / 4), dim3(64, 4), 0, stream>>>(positions, Qb, Kb);
    attn_kernel<<<dim3(8, NH), 512, 0, stream>>>(Qb, Kb, Vt, attnb);
    gemm9_kernel<1><<<256, 512, 0, stream>>>(attnb, Wot, nullptr,
                                             nullptr, nullptr, nullptr, out);
  } else {
    short* Qb    = (short*)(ws);
    short* Kb    = (short*)(ws + 16 * MB);
    short* Vb    = (short*)(ws + 32 * MB);
    short* Vt    = (short*)(ws + 48 * MB);
    short* attnb = (short*)(ws + 64 * MB);

    gemm_kernel<0, 0><<<dim3(16, 96), 256, 0, stream>>>(hidden, w_qkv, b_qkv, 3 * HID,
                                                        Qb, Kb, Vb, nullptr);
    rope_kernel<<<dim3(S_LEN, NH / 4), dim3(64, 4), 0, stream>>>(positions, Qb, Kb);
    vtrans_kernel<<<dim3(S_LEN / 64, HD / 64, NH), 256, 0, stream>>>(Vb, Vt);
    attn_kernel<<<dim3(8, NH), 512, 0, stream>>>(Qb, Kb, Vt, attnb);
    gemm_kernel<1, 1><<<dim3(16, 32), 256, 0, stream>>>(attnb, w_o, nullptr, HID,
                                                        nullptr, nullptr, nullptr, out);
  }
}

// Round 16
// 457.487 us; speedup vs baseline: 1.0577x; 1.0100x over previous
//
#include <hip/hip_runtime.h>
#include <hip/hip_bf16.h>

#define S_LEN 2048
#define HID   4096
#define NH    32
#define HD    128
#define KD    4096

typedef __attribute__((ext_vector_type(4))) float f32x4;
typedef __attribute__((ext_vector_type(8))) short s16x8;
typedef __attribute__((ext_vector_type(4))) short s16x4;

#define AS1 __attribute__((address_space(1)))
#define AS3 __attribute__((address_space(3)))

__device__ __forceinline__ void gl_lds16(const void* g, void* l) {
  __builtin_amdgcn_global_load_lds((const AS1 void*)g, (AS3 void*)l, 16, 0, 0);
}

__device__ inline short f2bf(float f) {
  union { float f; unsigned u; } v; v.f = f;
  return (short)((v.u + 0x7fffu + ((v.u >> 16) & 1u)) >> 16);
}
__device__ inline float bf2f(short s) {
  union { unsigned u; float f; } v; v.u = ((unsigned)(unsigned short)s) << 16;
  return v.f;
}
__device__ inline unsigned packbf(float a, float b) {
  return (unsigned)(unsigned short)f2bf(a) | ((unsigned)(unsigned short)f2bf(b) << 16);
}

// ============ one-time converts ============
__global__ __launch_bounds__(256)
void cvt_kernel(const float* __restrict__ A, short* __restrict__ Ab) {
  const size_t i = ((size_t)blockIdx.x * 256 + threadIdx.x) * 8;
  f32x4 v0 = *(const f32x4*)&A[i];
  f32x4 v1 = *(const f32x4*)&A[i + 4];
  s16x8 r;
  r[0]=f2bf(v0[0]); r[1]=f2bf(v0[1]); r[2]=f2bf(v0[2]); r[3]=f2bf(v0[3]);
  r[4]=f2bf(v1[0]); r[5]=f2bf(v1[1]); r[6]=f2bf(v1[2]); r[7]=f2bf(v1[3]);
  *(s16x8*)&Ab[i] = r;
}

// W [KD][N] f32 -> Wt [N][KD] bf16
__global__ __launch_bounds__(256)
void transcvt_kernel(const float* __restrict__ W, short* __restrict__ Wt, const int N) {
  __shared__ float tile[64][65];
  const int k0 = blockIdx.x * 64, n0 = blockIdx.y * 64;
  const int t = threadIdx.x;
#pragma unroll
  for (int i = 0; i < 16; ++i) {
    const int e = i * 256 + t;
    const int k = e >> 6, n = e & 63;
    tile[n][k] = W[(size_t)(k0 + k) * N + n0 + n];
  }
  __syncthreads();
  const int nn = t >> 2, ks = (t & 3) * 16;
  s16x8 a, b;
#pragma unroll
  for (int i = 0; i < 8; i++) a[i] = f2bf(tile[nn][ks + i]);
#pragma unroll
  for (int i = 0; i < 8; i++) b[i] = f2bf(tile[nn][ks + 8 + i]);
  *(s16x8*)&Wt[(size_t)(n0 + nn) * KD + k0 + ks]     = a;
  *(s16x8*)&Wt[(size_t)(n0 + nn) * KD + k0 + ks + 8] = b;
}

// ============ gemm9: BM=256 BN=128, 8 waves (4Mx2N), wave-tile 64x64, ring-3, ============
// counted vmcnt(3), XOR-swizzled LDS, 2 blocks/CU. V written DIRECTLY transposed to Vt.
template<int EPI>
__global__ __launch_bounds__(512, 4)
void gemm9_kernel(const short* __restrict__ A, const short* __restrict__ Bt,
                  const float* __restrict__ bias,
                  short* __restrict__ Qb, short* __restrict__ Kb, short* __restrict__ Vt,
                  float* __restrict__ Cout)
{
  __shared__ char sm[3][24576] __attribute__((aligned(128)));
  const int KD2 = KD * 2;
  const int bid = blockIdx.x;
  const int xcd = bid & 7, idx = bid >> 3;
  const int m0 = (idx & 7) * 256;
  const int n0 = (xcd * ((EPI == 0) ? 12 : 4) + (idx >> 3)) * 128;

  const int t = threadIdx.x, lane = t & 63, c = lane & 15, g = lane >> 4;
  const int w = t >> 6, wr = w >> 1, wc = w & 1;
  const int flip = ((c >> 1) & 7) << 4;
  const int laneA = wr * 4096 + ((c * 64 + g * 16) ^ flip);
  const int laneB = 16384 + wc * 4096 + ((c * 64 + g * 16) ^ flip);

  const char* srcA[2];
  const char* srcB0;
#pragma unroll
  for (int j = 0; j < 2; ++j) {
    const int la = j * 8192 + t * 16;
    const int ls = la ^ ((la >> 3) & 0x70);
    srcA[j] = (const char*)A + (size_t)(m0 + (ls >> 6)) * KD2 + (ls & 63);
  }
  {
    const int la = t * 16;
    const int ls = la ^ ((la >> 3) & 0x70);
    srcB0 = (const char*)Bt + (size_t)(n0 + (ls >> 6)) * KD2 + (ls & 63);
  }

  f32x4 acc[4][4];
#pragma unroll
  for (int i = 0; i < 4; i++)
#pragma unroll
    for (int j = 0; j < 4; j++) acc[i][j] = (f32x4){0.f, 0.f, 0.f, 0.f};

#define STG9(S, H) do {                                       \
    const size_t ko_ = (size_t)(H) * 64;                      \
    gl_lds16(srcA[0] + ko_, sm[S] + t * 16);                  \
    gl_lds16(srcA[1] + ko_, sm[S] + 8192  + t * 16);          \
    gl_lds16(srcB0   + ko_, sm[S] + 16384 + t * 16);          \
  } while (0)

#define COMP9(S) do {                                                      \
    const char* b_ = sm[S];                                                \
    s16x8 a_[4], bb_[4];                                                   \
    _Pragma("unroll")                                                      \
    for (int mi = 0; mi < 4; ++mi) a_[mi] = *(const s16x8*)(b_ + laneA + mi * 1024); \
    _Pragma("unroll")                                                      \
    for (int ni = 0; ni < 4; ++ni) bb_[ni] = *(const s16x8*)(b_ + laneB + ni * 1024); \
    __builtin_amdgcn_s_setprio(1);                                         \
    _Pragma("unroll")                                                      \
    for (int mi = 0; mi < 4; ++mi)                                         \
      _Pragma("unroll")                                                    \
      for (int ni = 0; ni < 4; ++ni)                                       \
        acc[mi][ni] = __builtin_amdgcn_mfma_f32_16x16x32_bf16(a_[mi], bb_[ni], acc[mi][ni], 0, 0, 0); \
    __builtin_amdgcn_s_setprio(0);                                         \
  } while (0)

#define WAIT3 asm volatile("s_waitcnt vmcnt(3)" ::: "memory")
#define WAIT0 asm volatile("s_waitcnt vmcnt(0)" ::: "memory")
#define BARR  do { __builtin_amdgcn_s_barrier(); asm volatile("" ::: "memory"); } while (0)

  STG9(0, 0); STG9(1, 1);
  for (int j = 0; j < 42; ++j) {
    const int h = 3 * j;
    WAIT3; BARR; STG9(2, h + 2); COMP9(0);
    WAIT3; BARR; STG9(0, h + 3); COMP9(1);
    WAIT3; BARR; STG9(1, h + 4); COMP9(2);
  }
  WAIT3; BARR; COMP9(0);
  WAIT0; BARR; COMP9(1);

#undef STG9
#undef COMP9
#undef WAIT3
#undef WAIT0
#undef BARR

  if (EPI == 0) {
    const int which = n0 >> 12;        // block-uniform (n0 is 128-aligned)
    if (which == 2) {
      // V: write directly transposed -> Vt[h][d][s]
#pragma unroll
      for (int ni = 0; ni < 4; ++ni) {
        const int ncol = n0 + wc * 64 + ni * 16 + c;
        const int h = (ncol >> 7) & 31;
        const int dcl = ncol & 127;
        const float bv = bias[ncol];
#pragma unroll
        for (int mi = 0; mi < 4; ++mi) {
          const int row0 = m0 + wr * 64 + mi * 16 + g * 4;
          s16x4 pk;
#pragma unroll
          for (int jj = 0; jj < 4; ++jj) pk[jj] = f2bf(acc[mi][ni][jj] + bv);
          *(s16x4*)&Vt[((size_t)h * HD + dcl) * S_LEN + row0] = pk;
        }
      }
    } else {
      short* dst = (which == 0) ? Qb : Kb;
#pragma unroll
      for (int ni = 0; ni < 4; ++ni) {
        const int ncol = n0 + wc * 64 + ni * 16 + c;
        const int h = (ncol >> 7) & 31;
        const int dcl = ncol & 127;
        const float bv = bias[ncol];
#pragma unroll
        for (int mi = 0; mi < 4; ++mi)
#pragma unroll
          for (int jj = 0; jj < 4; ++jj) {
            const int row = m0 + wr * 64 + mi * 16 + g * 4 + jj;
            dst[((size_t)h * S_LEN + row) * HD + dcl] = f2bf(acc[mi][ni][jj] + bv);
          }
      }
    }
  } else {
#pragma unroll
    for (int ni = 0; ni < 4; ++ni) {
      const int ncol = n0 + wc * 64 + ni * 16 + c;
#pragma unroll
      for (int mi = 0; mi < 4; ++mi)
#pragma unroll
        for (int jj = 0; jj < 4; ++jj) {
          const int row = m0 + wr * 64 + mi * 16 + g * 4 + jj;
          Cout[(size_t)row * HID + ncol] = acc[mi][ni][jj];
        }
    }
  }
}

// ============ fallback GEMM (reg-staged) ============
template<int EPI, int ABF16>
__global__ __launch_bounds__(256)
void gemm_kernel(const void* __restrict__ Av, const float* __restrict__ B,
                 const float* __restrict__ bias, const int N,
                 short* __restrict__ Qb, short* __restrict__ Kb, short* __restrict__ Vb,
                 float* __restrict__ Cout)
{
  __shared__ short As[128][40];
  __shared__ short Bs[128][40];
  const int m0 = blockIdx.x * 128;
  const int nb = blockIdx.y * 128;
  const int t  = threadIdx.x;
  const int w = t >> 6, lane = t & 63, c = lane & 15, g = lane >> 4;
  const int wm = (w >> 1) * 64, wn = (w & 1) * 64;

  f32x4 acc[4][4];
#pragma unroll
  for (int i = 0; i < 4; i++)
#pragma unroll
    for (int j = 0; j < 4; j++) acc[i][j] = (f32x4){0.f, 0.f, 0.f, 0.f};

  const int ar = t >> 3;
  const int ac = (t & 7) * 4;
  const int bn = t & 127;
  const int bkq = (t >> 7) * 16;

  for (int k0 = 0; k0 < KD; k0 += 32) {
#pragma unroll
    for (int rr = 0; rr < 4; rr++) {
      const int row = rr * 32 + ar;
      if (ABF16) {
        *(s16x4*)&As[row][ac] =
          *(const s16x4*)((const short*)Av + (size_t)(m0 + row) * KD + k0 + ac);
      } else {
        f32x4 v = *(const f32x4*)((const float*)Av + (size_t)(m0 + row) * KD + k0 + ac);
        s16x4 pk;
        pk[0] = f2bf(v[0]); pk[1] = f2bf(v[1]); pk[2] = f2bf(v[2]); pk[3] = f2bf(v[3]);
        *(s16x4*)&As[row][ac] = pk;
      }
    }
    const float* pB = B + (size_t)(k0 + bkq) * N + nb + bn;
    s16x8 b0, b1;
#pragma unroll
    for (int i = 0; i < 8; i++) b0[i] = f2bf(pB[(size_t)i * N]);
#pragma unroll
    for (int i = 0; i < 8; i++) b1[i] = f2bf(pB[(size_t)(i + 8) * N]);
    *(s16x8*)&Bs[bn][bkq]     = b0;
    *(s16x8*)&Bs[bn][bkq + 8] = b1;
    __syncthreads();
    s16x8 af[4], bfr[4];
#pragma unroll
    for (int i = 0; i < 4; i++) af[i]  = *(const s16x8*)&As[wm + i * 16 + c][g * 8];
#pragma unroll
    for (int i = 0; i < 4; i++) bfr[i] = *(const s16x8*)&Bs[wn + i * 16 + c][g * 8];
#pragma unroll
    for (int mi = 0; mi < 4; mi++)
#pragma unroll
      for (int ni = 0; ni < 4; ni++)
        acc[mi][ni] = __builtin_amdgcn_mfma_f32_16x16x32_bf16(af[mi], bfr[ni], acc[mi][ni], 0, 0, 0);
    __syncthreads();
  }

  if (EPI == 0) {
    const int which = nb >> 12;
    const int h = (nb & 4095) >> 7;
    short* dst = (which == 0) ? Qb : ((which == 1) ? Kb : Vb);
#pragma unroll
    for (int ni = 0; ni < 4; ni++) {
      const int d = wn + ni * 16 + c;
      const float bv = bias[nb + d];
#pragma unroll
      for (int mi = 0; mi < 4; mi++)
#pragma unroll
        for (int j = 0; j < 4; j++) {
          const int row = m0 + wm + mi * 16 + g * 4 + j;
          dst[((size_t)h * S_LEN + row) * HD + d] = f2bf(acc[mi][ni][j] + bv);
        }
    }
  } else {
#pragma unroll
    for (int ni = 0; ni < 4; ni++) {
      const int n = nb + wn + ni * 16 + c;
#pragma unroll
      for (int mi = 0; mi < 4; mi++)
#pragma unroll
        for (int j = 0; j < 4; j++) {
          const int row = m0 + wm + mi * 16 + g * 4 + j;
          Cout[(size_t)row * N + n] = acc[mi][ni][j];
        }
    }
  }
}

// ============ RoPE (Q scale folds 1/sqrt(HD) * log2(e) -> softmax in base 2) ============
__global__ void rope_kernel(const int* __restrict__ positions,
                            short* __restrict__ Qb, short* __restrict__ Kb)
{
  const int s = blockIdx.x;
  const int h = blockIdx.y * 4 + threadIdx.y;
  const int d = threadIdx.x;
  const float pos = (float)positions[s];
  const float inv_freq = exp2f(-(float)d * 0.20762050593046014f);
  const float ang = pos * inv_freq;
  float sn, cs;
  sincosf(ang, &sn, &cs);
  const size_t base = ((size_t)h * S_LEN + s) * HD + d;
  const float scale = 0.12751744416058255f;   // (1/sqrt(128)) * log2(e)
  float x1 = bf2f(Qb[base]), x2 = bf2f(Qb[base + 64]);
  Qb[base]      = f2bf((x1 * cs - x2 * sn) * scale);
  Qb[base + 64] = f2bf((x2 * cs + x1 * sn) * scale);
  x1 = bf2f(Kb[base]); x2 = bf2f(Kb[base + 64]);
  Kb[base]      = f2bf(x1 * cs - x2 * sn);
  Kb[base + 64] = f2bf(x2 * cs + x1 * sn);
}

// ============ V -> Vt [NH][HD][S] (fallback path only) ============
__global__ __launch_bounds__(256)
void vtrans_kernel(const short* __restrict__ V, short* __restrict__ Vt)
{
  __shared__ short tile[64][72];
  const int h = blockIdx.z;
  const int s0 = blockIdx.x * 64;
  const int d0 = blockIdx.y * 64;
  const int tx = threadIdx.x & 63, ty = threadIdx.x >> 6;
  for (int r = ty; r < 64; r += 4)
    tile[r][tx] = V[((size_t)h * S_LEN + s0 + r) * HD + d0 + tx];
  __syncthreads();
  for (int r = ty; r < 64; r += 4)
    Vt[((size_t)h * HD + d0 + r) * S_LEN + s0 + tx] = tile[tx][r];
}

// ============ causal flash attention v6: paired q-panels, base-2 softmax, ============
// XCD-grouped 1D grid: all 8 panel-blocks of a head share bid%8 -> same XCD L2.
__global__ __launch_bounds__(512)
void attn_kernel(const short* __restrict__ Q, const short* __restrict__ Kg,
                 const short* __restrict__ Vtg, short* __restrict__ attn_out)
{
  __shared__ short Ks[2][64][128];
  __shared__ short Vs[2][128][72];
  const int bid = blockIdx.x;                      // 0..255
  const int h  = (bid & 7) * 4 + (bid >> 6);       // head -> fixed XCD (bid%8)
  const int ib = (bid >> 3) & 7;                   // panel index 0..7
  const int q0a = ib * 128;
  const int q0b = (15 - ib) * 128;
  const int nt0 = 2 * ib + 2;
  const int nt1 = 32 - 2 * ib;
  const int t = threadIdx.x;
  const int w = t >> 6, lane = t & 63, c = lane & 15, g = lane >> 4;
  const short* Qh = Q   + (size_t)h * S_LEN * HD;
  const short* Kh = Kg  + (size_t)h * S_LEN * HD;
  const short* Vh = Vtg + (size_t)h * HD * S_LEN;

  const int krow = t >> 4, kch = t & 15;
  const int vrow = t >> 3, vch = t & 7;
  const int ksw = (kch ^ ((krow & 3) | ((krow >> 1) & 4))) * 16;

  const int rbase = (c >> 2) * 8 + (c & 3);
  const int sb = (rbase & 3) | ((rbase >> 1) & 4);
  int koff[4];
#pragma unroll
  for (int di = 0; di < 4; ++di) koff[di] = ((di * 4 + g) ^ sb) * 16;

  const int qga = q0a + w * 16 + c;
  const int qgb = q0b + w * 16 + c;
  s16x8 qfa[4], qfb[4];
#pragma unroll
  for (int di = 0; di < 4; di++) {
    qfa[di] = *(const s16x8*)&Qh[(size_t)qga * HD + di * 32 + g * 8];
    qfb[di] = *(const s16x8*)&Qh[(size_t)qgb * HD + di * 32 + g * 8];
  }

  f32x4 oa[8], ob[8];
#pragma unroll
  for (int dt = 0; dt < 8; dt++) {
    oa[dt] = (f32x4){0.f, 0.f, 0.f, 0.f};
    ob[dt] = (f32x4){0.f, 0.f, 0.f, 0.f};
  }
  float m_a = -3.0e38f, l_a = 0.f, m_b = -3.0e38f, l_b = 0.f;

#define SM_PANEL(SA, SB, SC, SD, QG, FULL, MR, LR, OARR, PB0, PB1) do {        \
    float v_[16];                                                              \
    if (FULL) {                                                                \
      _Pragma("unroll")                                                        \
      for (int j = 0; j < 4; ++j) {                                            \
        v_[j] = SA[j]; v_[4 + j] = SB[j]; v_[8 + j] = SC[j]; v_[12 + j] = SD[j]; \
      }                                                                        \
    } else {                                                                   \
      _Pragma("unroll")                                                        \
      for (int j = 0; j < 4; ++j) {                                            \
        v_[j]      = (kb + 8 * g + j          <= (QG)) ? SA[j] : -__builtin_inff(); \
        v_[4 + j]  = (kb + 8 * g + 4 + j      <= (QG)) ? SB[j] : -__builtin_inff(); \
        v_[8 + j]  = (kb + 32 + 8 * g + j     <= (QG)) ? SC[j] : -__builtin_inff(); \
        v_[12 + j] = (kb + 32 + 8 * g + 4 + j <= (QG)) ? SD[j] : -__builtin_inff(); \
      }                                                                        \
    }                                                                          \
    float mx_ = v_[0];                                                         \
    _Pragma("unroll")                                                          \
    for (int ii = 1; ii < 16; ++ii) mx_ = fmaxf(mx_, v_[ii]);                  \
    mx_ = fmaxf(mx_, __shfl_xor(mx_, 16, 64));                                 \
    mx_ = fmaxf(mx_, __shfl_xor(mx_, 32, 64));                                 \
    const float mn_ = fmaxf(MR, mx_);                                          \
    if (!__all(mn_ - MR <= 8.0f)) {                                            \
      const float al_ = exp2f(MR - mn_);                                       \
      LR *= al_;                                                               \
      _Pragma("unroll")                                                        \
      for (int dt = 0; dt < 8; ++dt)                                           \
        _Pragma("unroll")                                                      \
        for (int j = 0; j < 4; ++j) OARR[dt][j] *= al_;                        \
      MR = mn_;                                                                \
    }                                                                          \
    float p_[16], rs_ = 0.f;                                                   \
    _Pragma("unroll")                                                          \
    for (int ii = 0; ii < 16; ++ii) { p_[ii] = exp2f(v_[ii] - MR); rs_ += p_[ii]; } \
    LR += rs_;                                                                 \
    union { s16x8 v8; unsigned u[4]; } pu0_, pu1_;                             \
    pu0_.u[0] = packbf(p_[0], p_[1]);   pu0_.u[1] = packbf(p_[2], p_[3]);      \
    pu0_.u[2] = packbf(p_[4], p_[5]);   pu0_.u[3] = packbf(p_[6], p_[7]);      \
    pu1_.u[0] = packbf(p_[8], p_[9]);   pu1_.u[1] = packbf(p_[10], p_[11]);    \
    pu1_.u[2] = packbf(p_[12], p_[13]); pu1_.u[3] = packbf(p_[14], p_[15]);    \
    PB0 = pu0_.v8; PB1 = pu1_.v8;                                              \
  } while (0)

  {
#pragma unroll
    for (int i = 0; i < 2; ++i) {
      s16x8 gK = *(const s16x8*)&Kh[(size_t)(i * 32 + krow) * HD + kch * 8];
      s16x8 gV = *(const s16x8*)&Vh[(size_t)(i * 64 + vrow) * S_LEN + vch * 8];
      *(s16x8*)((char*)&Ks[0][0][0] + (i * 32 + krow) * 256 + ksw) = gK;
      *(s16x8*)&Vs[0][i * 64 + vrow][vch * 8] = gV;
    }
  }
  __syncthreads();

  for (int kt = 0; kt < nt1; kt++) {
    const int cur = kt & 1;
    const int kb = kt * 64;
    const bool do0 = (kt < nt0);
    s16x8 gK0, gK1, gV0, gV1;
    if (kt + 1 < nt1) {
      gK0 = *(const s16x8*)&Kh[(size_t)(kb + 64 + krow) * HD + kch * 8];
      gK1 = *(const s16x8*)&Kh[(size_t)(kb + 96 + krow) * HD + kch * 8];
      gV0 = *(const s16x8*)&Vh[(size_t)vrow * S_LEN + kb + 64 + vch * 8];
      gV1 = *(const s16x8*)&Vh[(size_t)(64 + vrow) * S_LEN + kb + 64 + vch * 8];
    }
    f32x4 bA = (f32x4){0,0,0,0}, bB = (f32x4){0,0,0,0};
    f32x4 bC = (f32x4){0,0,0,0}, bD = (f32x4){0,0,0,0};
    f32x4 aA = (f32x4){0,0,0,0}, aB = (f32x4){0,0,0,0};
    f32x4 aC = (f32x4){0,0,0,0}, aD = (f32x4){0,0,0,0};
    const char* kbase = (const char*)&Ks[cur][0][0] + rbase * 256;
    __builtin_amdgcn_s_setprio(1);
    if (do0) {
#pragma unroll
      for (int di = 0; di < 4; ++di) {
        const char* p = kbase + koff[di];
        s16x8 kA = *(const s16x8*)(p);
        s16x8 kB = *(const s16x8*)(p + 1024);
        s16x8 kC = *(const s16x8*)(p + 8192);
        s16x8 kD = *(const s16x8*)(p + 9216);
        bA = __builtin_amdgcn_mfma_f32_16x16x32_bf16(kA, qfb[di], bA, 0, 0, 0);
        bB = __builtin_amdgcn_mfma_f32_16x16x32_bf16(kB, qfb[di], bB, 0, 0, 0);
        bC = __builtin_amdgcn_mfma_f32_16x16x32_bf16(kC, qfb[di], bC, 0, 0, 0);
        bD = __builtin_amdgcn_mfma_f32_16x16x32_bf16(kD, qfb[di], bD, 0, 0, 0);
        aA = __builtin_amdgcn_mfma_f32_16x16x32_bf16(kA, qfa[di], aA, 0, 0, 0);
        aB = __builtin_amdgcn_mfma_f32_16x16x32_bf16(kB, qfa[di], aB, 0, 0, 0);
        aC = __builtin_amdgcn_mfma_f32_16x16x32_bf16(kC, qfa[di], aC, 0, 0, 0);
        aD = __builtin_amdgcn_mfma_f32_16x16x32_bf16(kD, qfa[di], aD, 0, 0, 0);
      }
    } else {
#pragma unroll
      for (int di = 0; di < 4; ++di) {
        const char* p = kbase + koff[di];
        s16x8 kA = *(const s16x8*)(p);
        s16x8 kB = *(const s16x8*)(p + 1024);
        s16x8 kC = *(const s16x8*)(p + 8192);
        s16x8 kD = *(const s16x8*)(p + 9216);
        bA = __builtin_amdgcn_mfma_f32_16x16x32_bf16(kA, qfb[di], bA, 0, 0, 0);
        bB = __builtin_amdgcn_mfma_f32_16x16x32_bf16(kB, qfb[di], bB, 0, 0, 0);
        bC = __builtin_amdgcn_mfma_f32_16x16x32_bf16(kC, qfb[di], bC, 0, 0, 0);
        bD = __builtin_amdgcn_mfma_f32_16x16x32_bf16(kD, qfb[di], bD, 0, 0, 0);
      }
    }
    __builtin_amdgcn_s_setprio(0);
    s16x8 pb0, pb1, pa0, pa1;
    const bool fullb = (kb + 64 <= q0b);
    SM_PANEL(bA, bB, bC, bD, qgb, fullb, m_b, l_b, ob, pb0, pb1);
    if (do0) {
      const bool fulla = (kb + 64 <= q0a);
      SM_PANEL(aA, aB, aC, aD, qga, fulla, m_a, l_a, oa, pa0, pa1);
    }
    __builtin_amdgcn_s_setprio(1);
    if (do0) {
#pragma unroll
      for (int dt = 0; dt < 8; dt++) {
        s16x8 vf0 = *(const s16x8*)&Vs[cur][dt * 16 + c][g * 8];
        s16x8 vf1 = *(const s16x8*)&Vs[cur][dt * 16 + c][32 + g * 8];
        ob[dt] = __builtin_amdgcn_mfma_f32_16x16x32_bf16(vf0, pb0, ob[dt], 0, 0, 0);
        ob[dt] = __builtin_amdgcn_mfma_f32_16x16x32_bf16(vf1, pb1, ob[dt], 0, 0, 0);
        oa[dt] = __builtin_amdgcn_mfma_f32_16x16x32_bf16(vf0, pa0, oa[dt], 0, 0, 0);
        oa[dt] = __builtin_amdgcn_mfma_f32_16x16x32_bf16(vf1, pa1, oa[dt], 0, 0, 0);
      }
    } else {
#pragma unroll
      for (int dt = 0; dt < 8; dt++) {
        s16x8 vf0 = *(const s16x8*)&Vs[cur][dt * 16 + c][g * 8];
        s16x8 vf1 = *(const s16x8*)&Vs[cur][dt * 16 + c][32 + g * 8];
        ob[dt] = __builtin_amdgcn_mfma_f32_16x16x32_bf16(vf0, pb0, ob[dt], 0, 0, 0);
        ob[dt] = __builtin_amdgcn_mfma_f32_16x16x32_bf16(vf1, pb1, ob[dt], 0, 0, 0);
      }
    }
    __builtin_amdgcn_s_setprio(0);
    __syncthreads();
    if (kt + 1 < nt1) {
      *(s16x8*)((char*)&Ks[cur ^ 1][0][0] + krow * 256 + ksw)        = gK0;
      *(s16x8*)((char*)&Ks[cur ^ 1][0][0] + (32 + krow) * 256 + ksw) = gK1;
      *(s16x8*)&Vs[cur ^ 1][vrow][vch * 8]      = gV0;
      *(s16x8*)&Vs[cur ^ 1][64 + vrow][vch * 8] = gV1;
    }
    __syncthreads();
  }
#undef SM_PANEL

  l_b += __shfl_xor(l_b, 16, 64);  l_b += __shfl_xor(l_b, 32, 64);
  l_a += __shfl_xor(l_a, 16, 64);  l_a += __shfl_xor(l_a, 32, 64);
  const float inv_b = 1.0f / l_b;
  const float inv_a = 1.0f / l_a;
#pragma unroll
  for (int dt = 0; dt < 8; dt++) {
    s16x4 pkb, pka;
#pragma unroll
    for (int j = 0; j < 4; j++) {
      pkb[j] = f2bf(ob[dt][j] * inv_b);
      pka[j] = f2bf(oa[dt][j] * inv_a);
    }
    *(s16x4*)&attn_out[(size_t)qgb * HID + h * HD + dt * 16 + g * 4] = pkb;
    *(s16x4*)&attn_out[(size_t)qga * HID + h * HD + dt * 16 + g * 4] = pka;
  }
}

extern "C" void kernel_launch(void* const* d_in, const int* in_sizes, int n_in,
                              void* d_out, int out_size, void* d_ws, size_t ws_size,
                              hipStream_t stream)
{
  const int*   positions = (const int*)d_in[0];
  const float* hidden    = (const float*)d_in[1];
  const float* w_qkv     = (const float*)d_in[2];
  const float* b_qkv     = (const float*)d_in[3];
  const float* w_o       = (const float*)d_in[4];
  float* out = (float*)d_out;

  char* ws = (char*)d_ws;
  const size_t MB = (size_t)1 << 20;

  if (ws_size >= 224 * MB) {
    short* Ah    = (short*)(ws);                 // 16 MB  bf16 [S][KD]
    short* Wqt   = (short*)(ws + 16 * MB);       // 96 MB  bf16 [3*HID][KD]
    short* Wot   = (short*)(ws + 112 * MB);      // 32 MB  bf16 [HID][KD]
    short* Qb    = (short*)(ws + 144 * MB);      // 16 MB
    short* Kb    = (short*)(ws + 160 * MB);      // 16 MB
    short* Vt    = (short*)(ws + 192 * MB);      // 16 MB  [NH][HD][S] (written by gemm9)
    short* attnb = (short*)(ws + 208 * MB);      // 16 MB  bf16 [S][HID]

    cvt_kernel<<<4096, 256, 0, stream>>>(hidden, Ah);
    transcvt_kernel<<<dim3(KD / 64, 3 * HID / 64), 256, 0, stream>>>(w_qkv, Wqt, 3 * HID);
    transcvt_kernel<<<dim3(KD / 64, HID / 64), 256, 0, stream>>>(w_o, Wot, HID);
    gemm9_kernel<0><<<768, 512, 0, stream>>>(Ah, Wqt, b_qkv, Qb, Kb, Vt, nullptr);
    rope_kernel<<<dim3(S_LEN, NH / 4), dim3(64, 4), 0, stream>>>(positions, Qb, Kb);
    attn_kernel<<<256, 512, 0, stream>>>(Qb, Kb, Vt, attnb);
    gemm9_kernel<1><<<256, 512, 0, stream>>>(attnb, Wot, nullptr,
                                             nullptr, nullptr, nullptr, out);
  } else {
    short* Qb    = (short*)(ws);
    short* Kb    = (short*)(ws + 16 * MB);
    short* Vb    = (short*)(ws + 32 * MB);
    short* Vt    = (short*)(ws + 48 * MB);
    short* attnb = (short*)(ws + 64 * MB);

    gemm_kernel<0, 0><<<dim3(16, 96), 256, 0, stream>>>(hidden, w_qkv, b_qkv, 3 * HID,
                                                        Qb, Kb, Vb, nullptr);
    rope_kernel<<<dim3(S_LEN, NH / 4), dim3(64, 4), 0, stream>>>(positions, Qb, Kb);
    vtrans_kernel<<<dim3(S_LEN / 64, HD / 64, NH), 256, 0, stream>>>(Vb, Vt);
    attn_kernel<<<256, 512, 0, stream>>>(Qb, Kb, Vt, attnb);
    gemm_kernel<1, 1><<<dim3(16, 32), 256, 0, stream>>>(attnb, w_o, nullptr, HID,
                                                        nullptr, nullptr, nullptr, out);
  }
}